// Round 4
// baseline (274.803 us; speedup 1.0000x reference)
//
#include <hip/hip_runtime.h>
#include <stdint.h>

// ---------------------------------------------------------------------------
// MultiHeadAttention forward, MI355X/gfx950.  Round 4: fp32 I/O (per harness
// contract — reference dtypes are float32), bf16 MFMA compute internally.
// Rounds 1-2 NaN'd because fp32 inputs were read as bf16 (low-half words
// decode as bf16 inf/NaN ~1/256 of elements). Round 3 likely died on ws
// overflow (50 MB); this round uses exactly 32 MB of ws.
// Shapes: B=2 S=2048 D=1024 H=16 HD=64. M = B*S = 4096.
//   gemm_qkv: x(f32)@W(f32)^T -> Q,K [B,H,S,64] bf16, V^T [B,H,64,S] bf16
//   attn:     flash-style causal (bf16 MFMA) -> ctx [B,S,1024] bf16
//   gemm_out: ctx(bf16)@Wo(f32)^T + bo(f32) -> out FP32
// fp32 -> bf16 conversion happens in the GEMM staging path (registers),
// RTN via compiler cast (v_cvt_pk_bf16_f32 on gfx950).
// MFMA mfma_f32_16x16x32_bf16:
//   A-frag: lane(quad,l15) holds A[m=l15][k=quad*8+j]  (contig bf16x8)
//   B-frag: B[n=l15][k=quad*8+j];  C/D: col=l15, row=quad*4+reg  [m89]
// LDS rows padded (64->72, 128->136): 2-way bank aliasing max (free, m136).
// ---------------------------------------------------------------------------

typedef __bf16 bf16_t;
typedef __bf16 bf16x8 __attribute__((ext_vector_type(8)));
typedef float  f32x4  __attribute__((ext_vector_type(4)));
typedef uint32_t u32x4 __attribute__((ext_vector_type(4)));

#define MFMA16(A, B, C) __builtin_amdgcn_mfma_f32_16x16x32_bf16(A, B, C, 0, 0, 0)

// Load 8 source elements starting at p as 8 packed bf16 (one 16B LDS chunk).
__device__ __forceinline__ u32x4 ld8(const bf16_t* p) {
  return *(const u32x4*)p;
}
__device__ __forceinline__ u32x4 ld8(const float* p) {
  const float4 a = *(const float4*)p;
  const float4 b = *(const float4*)(p + 4);
  union { u32x4 v; bf16_t h[8]; } r;
  r.h[0] = (bf16_t)a.x; r.h[1] = (bf16_t)a.y;
  r.h[2] = (bf16_t)a.z; r.h[3] = (bf16_t)a.w;
  r.h[4] = (bf16_t)b.x; r.h[5] = (bf16_t)b.y;
  r.h[6] = (bf16_t)b.z; r.h[7] = (bf16_t)b.w;
  return r.v;
}

// ---------------------------------------------------------------------------
// GEMM core: D[m,n] = sum_k A[m,k] * W[n,k]  (A: 4096x1024, W: 1024x1024)
// Block 256 thr (4 waves), tile 128x128, BK=64, two-barrier K-loop.
// mode 0: Q/K [B,H,S,64] bf16; mode 1: V^T [B,H,64,S] bf16;
// mode 2: row-major FP32 + fp32 bias.
// ---------------------------------------------------------------------------
template <typename TA, typename TW>
__device__ __forceinline__ void gemm_core(const TA* __restrict__ A,
                                          const TW* __restrict__ W,
                                          bf16_t* __restrict__ D,
                                          float* __restrict__ Dout,
                                          const float* __restrict__ bias,
                                          int mode) {
  constexpr int LDT = 72;
  __shared__ __align__(16) bf16_t As[128 * LDT];
  __shared__ __align__(16) bf16_t Bs[128 * LDT];

  const int tid  = threadIdx.x;
  const int lane = tid & 63;
  const int w    = tid >> 6;
  const int quad = lane >> 4;
  const int l15  = lane & 15;
  const int bm   = blockIdx.y * 128;
  const int bn   = blockIdx.x * 128;
  const int wm   = (w >> 1) * 64;
  const int wn   = (w & 1) * 64;
  const int srow = tid >> 3;        // 0..31
  const int schk = tid & 7;         // 8-elem chunk 0..7

  f32x4 acc[4][4] = {};

  for (int k0 = 0; k0 < 1024; k0 += 64) {
    u32x4 ra[4], rb[4];
#pragma unroll
    for (int s2 = 0; s2 < 4; ++s2) {
      const int r = srow + s2 * 32;
      ra[s2] = ld8(A + (size_t)(bm + r) * 1024 + k0 + schk * 8);
      rb[s2] = ld8(W + (size_t)(bn + r) * 1024 + k0 + schk * 8);
    }
    __syncthreads();                // prior iter's LDS reads complete
#pragma unroll
    for (int s2 = 0; s2 < 4; ++s2) {
      const int r = srow + s2 * 32;
      *(u32x4*)&As[r * LDT + schk * 8] = ra[s2];
      *(u32x4*)&Bs[r * LDT + schk * 8] = rb[s2];
    }
    __syncthreads();                // staging visible to all waves

#pragma unroll
    for (int kk = 0; kk < 64; kk += 32) {
      const int co = kk + quad * 8;
      bf16x8 aF[4], bF[4];
#pragma unroll
      for (int mt = 0; mt < 4; ++mt)
        aF[mt] = *(const bf16x8*)&As[(wm + mt * 16 + l15) * LDT + co];
#pragma unroll
      for (int nt = 0; nt < 4; ++nt)
        bF[nt] = *(const bf16x8*)&Bs[(wn + nt * 16 + l15) * LDT + co];
#pragma unroll
      for (int mt = 0; mt < 4; ++mt)
#pragma unroll
        for (int nt = 0; nt < 4; ++nt)
          acc[mt][nt] = MFMA16(aF[mt], bF[nt], acc[mt][nt]);
    }
  }

  // Epilogue. C/D: col = l15, row = quad*4 + reg.
#pragma unroll
  for (int mt = 0; mt < 4; ++mt) {
#pragma unroll
    for (int nt = 0; nt < 4; ++nt) {
      const int n  = bn + wn + nt * 16 + l15;
      const int mb = bm + wm + mt * 16 + quad * 4;
      if (mode == 0) {               // Q/K: [B,H,S,64]
        const int h = n >> 6, hd = n & 63;
#pragma unroll
        for (int r = 0; r < 4; ++r) {
          const int m = mb + r;
          const int b = m >> 11, s = m & 2047;
          D[(size_t)b * 2097152 + (size_t)h * 131072 + (size_t)s * 64 + hd] =
              (bf16_t)acc[mt][nt][r];
        }
      } else if (mode == 1) {        // V^T: [B,H,64,S]; 4 consecutive tokens
        const int h = n >> 6, hd = n & 63;
        const int b = mb >> 11, s0 = mb & 2047;   // s0 % 4 == 0 -> 8B aligned
        union { uint64_t u; bf16_t h4[4]; } pk;
#pragma unroll
        for (int r = 0; r < 4; ++r) pk.h4[r] = (bf16_t)acc[mt][nt][r];
        *(uint64_t*)(D + (size_t)b * 2097152 + (size_t)h * 131072 +
                     (size_t)hd * 2048 + s0) = pk.u;
      } else {                       // out: row-major FP32 + fp32 bias
        const float bv = bias[n];
#pragma unroll
        for (int r = 0; r < 4; ++r) {
          const int m = mb + r;
          Dout[(size_t)m * 1024 + n] = acc[mt][nt][r] + bv;
        }
      }
    }
  }
}

__global__ __launch_bounds__(256, 2) void gemm_qkv(
    const float* __restrict__ X,  const float* __restrict__ Wq,
    const float* __restrict__ Wk, const float* __restrict__ Wv,
    bf16_t* __restrict__ Q, bf16_t* __restrict__ K, bf16_t* __restrict__ V) {
  const int z = blockIdx.z;
  const float* W = (z == 0) ? Wq : (z == 1) ? Wk : Wv;
  bf16_t*      D = (z == 0) ? Q  : (z == 1) ? K  : V;
  gemm_core<float, float>(X, W, D, nullptr, nullptr, (z == 2) ? 1 : 0);
}

__global__ __launch_bounds__(256, 2) void gemm_out(
    const bf16_t* __restrict__ ctx, const float* __restrict__ Wo,
    float* __restrict__ out, const float* __restrict__ bo) {
  gemm_core<bf16_t, float>(ctx, Wo, nullptr, out, bo, 2);
}

// ---------------------------------------------------------------------------
// Flash-style causal attention. Grid (16 q-tiles, 16 heads, 2 batch), 256 thr.
// Q,K: [B,H,S,64] bf16; V^T: [B,H,64,S] bf16; ctx: [B,S,1024] bf16.
// Wave w owns q-rows [w*32, w*32+32). LDS 69 KB -> 2 blocks/CU.
// ---------------------------------------------------------------------------
__global__ __launch_bounds__(256, 2) void attn(
    const bf16_t* __restrict__ Qw, const bf16_t* __restrict__ Kw,
    const bf16_t* __restrict__ Vw, bf16_t* __restrict__ ctx) {
  constexpr int LDK = 72, LDV = 136, LDP = 136;
  __shared__ __align__(16) bf16_t Ks[128 * LDK];
  __shared__ __align__(16) bf16_t Vts[64 * LDV];
  __shared__ __align__(16) bf16_t Ps[128 * LDP];

  const int tid  = threadIdx.x;
  const int lane = tid & 63;
  const int w    = tid >> 6;
  const int quad = lane >> 4;
  const int l15  = lane & 15;
  const int qt   = blockIdx.x;
  const int h    = blockIdx.y;
  const int b    = blockIdx.z;
  const size_t bh = (size_t)(b * 16 + h) * (size_t)(2048 * 64);
  const bf16_t* Qh = Qw + bh;
  const bf16_t* Kh = Kw + bh;
  const bf16_t* Vh = Vw + bh;       // [64][2048]

  const int srow = tid >> 3, schk = tid & 7;
  const int vrow = tid >> 4, vchk = tid & 15;

  bf16_t* Qs = Ps;                   // stage Q through Ps region (stride LDK)
  {
    u32x4 rq[4];
#pragma unroll
    for (int s2 = 0; s2 < 4; ++s2)
      rq[s2] = *(const u32x4*)(Qh + (size_t)(qt * 128 + srow + s2 * 32) * 64 + schk * 8);
#pragma unroll
    for (int s2 = 0; s2 < 4; ++s2)
      *(u32x4*)&Qs[(srow + s2 * 32) * LDK + schk * 8] = rq[s2];
  }
  __syncthreads();
  bf16x8 qF[2][2];
#pragma unroll
  for (int mt = 0; mt < 2; ++mt)
#pragma unroll
    for (int k2 = 0; k2 < 2; ++k2)
      qF[mt][k2] = *(const bf16x8*)
          &Qs[(w * 32 + mt * 16 + l15) * LDK + k2 * 32 + quad * 8];

  f32x4 O[2][4] = {};
  float mrow[2][4], lrow[2][4];
#pragma unroll
  for (int mt = 0; mt < 2; ++mt)
#pragma unroll
    for (int r = 0; r < 4; ++r) { mrow[mt][r] = -1e30f; lrow[mt][r] = 0.f; }

  const float sc_log2 = 0.125f * 1.44269504088896340736f;  // 1/sqrt(64)*log2e

  for (int kt = 0; kt <= qt; ++kt) {
    u32x4 rk[4], rv[4];
#pragma unroll
    for (int s2 = 0; s2 < 4; ++s2)
      rk[s2] = *(const u32x4*)(Kh + (size_t)(kt * 128 + srow + s2 * 32) * 64 + schk * 8);
#pragma unroll
    for (int s2 = 0; s2 < 4; ++s2)
      rv[s2] = *(const u32x4*)(Vh + (size_t)(vrow + s2 * 16) * 2048 + kt * 128 + vchk * 8);
    __syncthreads();   // prior-iter LDS reads (and iter0 qF reads) complete
#pragma unroll
    for (int s2 = 0; s2 < 4; ++s2)
      *(u32x4*)&Ks[(srow + s2 * 32) * LDK + schk * 8] = rk[s2];
#pragma unroll
    for (int s2 = 0; s2 < 4; ++s2)
      *(u32x4*)&Vts[(vrow + s2 * 16) * LDV + vchk * 8] = rv[s2];
    __syncthreads();

    // --- S = Q K^T ---
    f32x4 S[2][8] = {};
#pragma unroll
    for (int nt = 0; nt < 8; ++nt) {
      const int kr = nt * 16 + l15;
#pragma unroll
      for (int k2 = 0; k2 < 2; ++k2) {
        const bf16x8 kF = *(const bf16x8*)&Ks[kr * LDK + k2 * 32 + quad * 8];
#pragma unroll
        for (int mt = 0; mt < 2; ++mt)
          S[mt][nt] = MFMA16(qF[mt][k2], kF, S[mt][nt]);
      }
    }

    // --- causal mask + online softmax; P (bf16) to wave-private LDS rows ---
    const bool diag = (kt == qt);
#pragma unroll
    for (int mt = 0; mt < 2; ++mt) {
#pragma unroll
      for (int r = 0; r < 4; ++r) {
        const int q = w * 32 + mt * 16 + quad * 4 + r;
        float sv[8], mx = -1e30f;
#pragma unroll
        for (int nt = 0; nt < 8; ++nt) {
          float s = S[mt][nt][r];
          if (diag && (nt * 16 + l15 > q)) s = -1e30f;
          sv[nt] = s;
          mx = fmaxf(mx, s);
        }
#pragma unroll
        for (int d = 1; d < 16; d <<= 1) mx = fmaxf(mx, __shfl_xor(mx, d));
        const float mnew  = fmaxf(mrow[mt][r], mx);
        const float alpha = exp2f((mrow[mt][r] - mnew) * sc_log2);
        mrow[mt][r] = mnew;
        float rs = 0.f;
#pragma unroll
        for (int nt = 0; nt < 8; ++nt) {
          const float p = exp2f((sv[nt] - mnew) * sc_log2);
          rs += p;
          Ps[q * LDP + nt * 16 + l15] = (bf16_t)p;
        }
#pragma unroll
        for (int d = 1; d < 16; d <<= 1) rs += __shfl_xor(rs, d);
        lrow[mt][r] = lrow[mt][r] * alpha + rs;
#pragma unroll
        for (int nt = 0; nt < 4; ++nt) O[mt][nt][r] *= alpha;
      }
    }

    // --- O += P V  (wave-private Ps rows; same-wave RAW, no barrier) ---
#pragma unroll
    for (int kk = 0; kk < 128; kk += 32) {
      const int co = kk + quad * 8;
      bf16x8 pF[2], vF[4];
#pragma unroll
      for (int mt = 0; mt < 2; ++mt)
        pF[mt] = *(const bf16x8*)&Ps[(w * 32 + mt * 16 + l15) * LDP + co];
#pragma unroll
      for (int nt = 0; nt < 4; ++nt)
        vF[nt] = *(const bf16x8*)&Vts[(nt * 16 + l15) * LDV + co];
#pragma unroll
      for (int mt = 0; mt < 2; ++mt)
#pragma unroll
        for (int nt = 0; nt < 4; ++nt)
          O[mt][nt] = MFMA16(pF[mt], vF[nt], O[mt][nt]);
    }
  }

  // --- epilogue: normalize, store ctx [B,S,1024] bf16 ---
#pragma unroll
  for (int mt = 0; mt < 2; ++mt) {
#pragma unroll
    for (int r = 0; r < 4; ++r) {
      const int s    = qt * 128 + w * 32 + mt * 16 + quad * 4 + r;
      const float iv = 1.f / lrow[mt][r];
#pragma unroll
      for (int nt = 0; nt < 4; ++nt) {
        const int hd = nt * 16 + l15;
        ctx[(size_t)(b * 2048 + s) * 1024 + h * 64 + hd] =
            (bf16_t)(O[mt][nt][r] * iv);
      }
    }
  }
}

// ---------------------------------------------------------------------------
extern "C" void kernel_launch(void* const* d_in, const int* in_sizes, int n_in,
                              void* d_out, int out_size, void* d_ws, size_t ws_size,
                              hipStream_t stream) {
  const float* x  = (const float*)d_in[0];
  const float* Wq = (const float*)d_in[1];
  const float* Wk = (const float*)d_in[2];
  const float* Wv = (const float*)d_in[3];
  const float* Wo = (const float*)d_in[4];
  const float* bo = (const float*)d_in[5];
  bf16_t* ws   = (bf16_t*)d_ws;
  bf16_t* Qw   = ws;                  // 4M bf16 elems each
  bf16_t* Kw   = ws + 4194304;
  bf16_t* Vw   = ws + 8388608;        // [B,H,64,S]
  bf16_t* ctxw = ws + 12582912;       // total ws use: 32 MB
  float*  out  = (float*)d_out;       // fp32 per reference output dtype

  dim3 blk(256);
  gemm_qkv<<<dim3(8, 32, 3), blk, 0, stream>>>(x, Wq, Wk, Wv, Qw, Kw, Vw);
  attn<<<dim3(16, 16, 2), blk, 0, stream>>>(Qw, Kw, Vw, ctxw);
  gemm_out<<<dim3(8, 32, 1), blk, 0, stream>>>(ctxw, Wo, out, bo);
}

// Round 5
// 237.825 us; speedup vs baseline: 1.1555x; 1.1555x over previous
//
#include <hip/hip_runtime.h>
#include <stdint.h>

// ---------------------------------------------------------------------------
// MultiHeadAttention forward, MI355X/gfx950.  Round 5.
// fp32 I/O, bf16 MFMA compute. B=2 S=2048 D=1024 H=16 HD=64. M=4096.
// R5 changes vs R4 (passed, 274.8 us):
//  1) attn qt pairing: blockIdx.z==1 takes qt=15-x so CU-resident block pairs
//     (ids c, c+256; CU map is periodic-256) sum to 17 K-tiles -> no tail.
//  2) attn K/V software pipeline: prefetch next tile into regs after the
//     staging barrier, overlapping global loads with QK/softmax/PV compute.
//  3) ws_size-guarded bf16 pre-conversion of x + Wq/Wk/Wv/Wo (needs 48 MB ws)
//     -> halves GEMM staging bytes, removes cvt from hot loop. Fallback =
//     R4's proven fp32-staging path.
// MFMA mfma_f32_16x16x32_bf16 layouts [m89-verified]:
//   A-frag: lane(quad,l15) holds A[m=l15][k=quad*8+j]  (contig bf16x8)
//   B-frag: B[n=l15][k=quad*8+j];  C/D: col=l15, row=quad*4+reg
// LDS rows padded (64->72, 128->136): 2-way bank aliasing max (free, m136).
// ---------------------------------------------------------------------------

typedef __bf16 bf16_t;
typedef __bf16 bf16x8 __attribute__((ext_vector_type(8)));
typedef float  f32x4  __attribute__((ext_vector_type(4)));
typedef uint32_t u32x4 __attribute__((ext_vector_type(4)));

#define MFMA16(A, B, C) __builtin_amdgcn_mfma_f32_16x16x32_bf16(A, B, C, 0, 0, 0)

// Load 8 source elements at p as 8 packed bf16 (one 16B LDS chunk).
__device__ __forceinline__ u32x4 ld8(const bf16_t* p) {
  return *(const u32x4*)p;
}
__device__ __forceinline__ u32x4 ld8(const float* p) {
  const float4 a = *(const float4*)p;
  const float4 b = *(const float4*)(p + 4);
  union { u32x4 v; bf16_t h[8]; } r;
  r.h[0] = (bf16_t)a.x; r.h[1] = (bf16_t)a.y;
  r.h[2] = (bf16_t)a.z; r.h[3] = (bf16_t)a.w;
  r.h[4] = (bf16_t)b.x; r.h[5] = (bf16_t)b.y;
  r.h[6] = (bf16_t)b.z; r.h[7] = (bf16_t)b.w;
  return r.v;
}

// --- fp32 -> bf16 bulk converter (RTN via compiler cast) -------------------
__global__ __launch_bounds__(256) void cvt_bf16(const float* __restrict__ s,
                                                bf16_t* __restrict__ d, int n) {
  const int i4 = (blockIdx.x * 256 + threadIdx.x) * 4;
  if (i4 >= n) return;
  const float4 v = *(const float4*)(s + i4);
  union { uint64_t u; bf16_t h[4]; } pk;
  pk.h[0] = (bf16_t)v.x; pk.h[1] = (bf16_t)v.y;
  pk.h[2] = (bf16_t)v.z; pk.h[3] = (bf16_t)v.w;
  *(uint64_t*)(d + i4) = pk.u;
}

// ---------------------------------------------------------------------------
// GEMM core: D[m,n] = sum_k A[m,k] * W[n,k]  (A: 4096x1024, W: 1024x1024)
// Block 256 thr (4 waves), tile 128x128, BK=64, two-barrier K-loop.
// mode 0: Q/K [B,H,S,64] bf16; mode 1: V^T [B,H,64,S] bf16;
// mode 2: row-major FP32 + fp32 bias.
// ---------------------------------------------------------------------------
template <typename TA, typename TW>
__device__ __forceinline__ void gemm_core(const TA* __restrict__ A,
                                          const TW* __restrict__ W,
                                          bf16_t* __restrict__ D,
                                          float* __restrict__ Dout,
                                          const float* __restrict__ bias,
                                          int mode) {
  constexpr int LDT = 72;
  __shared__ __align__(16) bf16_t As[128 * LDT];
  __shared__ __align__(16) bf16_t Bs[128 * LDT];

  const int tid  = threadIdx.x;
  const int lane = tid & 63;
  const int w    = tid >> 6;
  const int quad = lane >> 4;
  const int l15  = lane & 15;
  const int bm   = blockIdx.y * 128;
  const int bn   = blockIdx.x * 128;
  const int wm   = (w >> 1) * 64;
  const int wn   = (w & 1) * 64;
  const int srow = tid >> 3;        // 0..31
  const int schk = tid & 7;         // 8-elem chunk 0..7

  f32x4 acc[4][4] = {};

  for (int k0 = 0; k0 < 1024; k0 += 64) {
    u32x4 ra[4], rb[4];
#pragma unroll
    for (int s2 = 0; s2 < 4; ++s2) {
      const int r = srow + s2 * 32;
      ra[s2] = ld8(A + (size_t)(bm + r) * 1024 + k0 + schk * 8);
      rb[s2] = ld8(W + (size_t)(bn + r) * 1024 + k0 + schk * 8);
    }
    __syncthreads();                // prior iter's LDS reads complete
#pragma unroll
    for (int s2 = 0; s2 < 4; ++s2) {
      const int r = srow + s2 * 32;
      *(u32x4*)&As[r * LDT + schk * 8] = ra[s2];
      *(u32x4*)&Bs[r * LDT + schk * 8] = rb[s2];
    }
    __syncthreads();                // staging visible to all waves

#pragma unroll
    for (int kk = 0; kk < 64; kk += 32) {
      const int co = kk + quad * 8;
      bf16x8 aF[4], bF[4];
#pragma unroll
      for (int mt = 0; mt < 4; ++mt)
        aF[mt] = *(const bf16x8*)&As[(wm + mt * 16 + l15) * LDT + co];
#pragma unroll
      for (int nt = 0; nt < 4; ++nt)
        bF[nt] = *(const bf16x8*)&Bs[(wn + nt * 16 + l15) * LDT + co];
#pragma unroll
      for (int mt = 0; mt < 4; ++mt)
#pragma unroll
        for (int nt = 0; nt < 4; ++nt)
          acc[mt][nt] = MFMA16(aF[mt], bF[nt], acc[mt][nt]);
    }
  }

  // Epilogue. C/D: col = l15, row = quad*4 + reg.
#pragma unroll
  for (int mt = 0; mt < 4; ++mt) {
#pragma unroll
    for (int nt = 0; nt < 4; ++nt) {
      const int n  = bn + wn + nt * 16 + l15;
      const int mb = bm + wm + mt * 16 + quad * 4;
      if (mode == 0) {               // Q/K: [B,H,S,64]
        const int h = n >> 6, hd = n & 63;
#pragma unroll
        for (int r = 0; r < 4; ++r) {
          const int m = mb + r;
          const int b = m >> 11, s = m & 2047;
          D[(size_t)b * 2097152 + (size_t)h * 131072 + (size_t)s * 64 + hd] =
              (bf16_t)acc[mt][nt][r];
        }
      } else if (mode == 1) {        // V^T: [B,H,64,S]; 4 consecutive tokens
        const int h = n >> 6, hd = n & 63;
        const int b = mb >> 11, s0 = mb & 2047;   // s0 % 4 == 0 -> 8B aligned
        union { uint64_t u; bf16_t h4[4]; } pk;
#pragma unroll
        for (int r = 0; r < 4; ++r) pk.h4[r] = (bf16_t)acc[mt][nt][r];
        *(uint64_t*)(D + (size_t)b * 2097152 + (size_t)h * 131072 +
                     (size_t)hd * 2048 + s0) = pk.u;
      } else {                       // out: row-major FP32 + fp32 bias
        const float bv = bias[n];
#pragma unroll
        for (int r = 0; r < 4; ++r) {
          const int m = mb + r;
          Dout[(size_t)m * 1024 + n] = acc[mt][nt][r] + bv;
        }
      }
    }
  }
}

template <typename TX, typename TW>
__global__ __launch_bounds__(256, 2) void gemm_qkv(
    const TX* __restrict__ X,  const TW* __restrict__ Wq,
    const TW* __restrict__ Wk, const TW* __restrict__ Wv,
    bf16_t* __restrict__ Q, bf16_t* __restrict__ K, bf16_t* __restrict__ V) {
  const int z = blockIdx.z;
  const TW* W = (z == 0) ? Wq : (z == 1) ? Wk : Wv;
  bf16_t*   D = (z == 0) ? Q  : (z == 1) ? K  : V;
  gemm_core<TX, TW>(X, W, D, nullptr, nullptr, (z == 2) ? 1 : 0);
}

template <typename TW>
__global__ __launch_bounds__(256, 2) void gemm_out(
    const bf16_t* __restrict__ ctx, const TW* __restrict__ Wo,
    float* __restrict__ out, const float* __restrict__ bo) {
  gemm_core<bf16_t, TW>(ctx, Wo, nullptr, out, bo, 2);
}

// ---------------------------------------------------------------------------
// Flash-style causal attention. Grid (16, 16 heads, 2 batch), 256 thr.
// qt remap: z==0 -> x, z==1 -> 15-x  (CU block-pairs sum to 17 K-tiles).
// Q,K: [B,H,S,64] bf16; V^T: [B,H,64,S] bf16; ctx: [B,S,1024] bf16.
// Wave w owns q-rows [w*32, w*32+32). LDS 69 KB -> 2 blocks/CU.
// K/V tiles prefetched into regs one iteration ahead (overlap with compute).
// ---------------------------------------------------------------------------
__global__ __launch_bounds__(256, 2) void attn(
    const bf16_t* __restrict__ Qw, const bf16_t* __restrict__ Kw,
    const bf16_t* __restrict__ Vw, bf16_t* __restrict__ ctx) {
  constexpr int LDK = 72, LDV = 136, LDP = 136;
  __shared__ __align__(16) bf16_t Ks[128 * LDK];
  __shared__ __align__(16) bf16_t Vts[64 * LDV];
  __shared__ __align__(16) bf16_t Ps[128 * LDP];

  const int tid  = threadIdx.x;
  const int lane = tid & 63;
  const int w    = tid >> 6;
  const int quad = lane >> 4;
  const int l15  = lane & 15;
  const int b    = blockIdx.z;
  const int qt   = (b == 0) ? blockIdx.x : 15 - blockIdx.x;  // pairing
  const int h    = blockIdx.y;
  const size_t bh = (size_t)(b * 16 + h) * (size_t)(2048 * 64);
  const bf16_t* Qh = Qw + bh;
  const bf16_t* Kh = Kw + bh;
  const bf16_t* Vh = Vw + bh;       // [64][2048]

  const int srow = tid >> 3, schk = tid & 7;
  const int vrow = tid >> 4, vchk = tid & 15;

  bf16_t* Qs = Ps;                   // stage Q through Ps region (stride LDK)
  {
    u32x4 rq[4];
#pragma unroll
    for (int s2 = 0; s2 < 4; ++s2)
      rq[s2] = *(const u32x4*)(Qh + (size_t)(qt * 128 + srow + s2 * 32) * 64 + schk * 8);
#pragma unroll
    for (int s2 = 0; s2 < 4; ++s2)
      *(u32x4*)&Qs[(srow + s2 * 32) * LDK + schk * 8] = rq[s2];
  }
  __syncthreads();
  bf16x8 qF[2][2];
#pragma unroll
  for (int mt = 0; mt < 2; ++mt)
#pragma unroll
    for (int k2 = 0; k2 < 2; ++k2)
      qF[mt][k2] = *(const bf16x8*)
          &Qs[(w * 32 + mt * 16 + l15) * LDK + k2 * 32 + quad * 8];

  f32x4 O[2][4] = {};
  float mrow[2][4], lrow[2][4];
#pragma unroll
  for (int mt = 0; mt < 2; ++mt)
#pragma unroll
    for (int r = 0; r < 4; ++r) { mrow[mt][r] = -1e30f; lrow[mt][r] = 0.f; }

  const float sc_log2 = 0.125f * 1.44269504088896340736f;  // 1/sqrt(64)*log2e

  // --- preload kt=0 K/V tiles into registers ---
  u32x4 rk[4], rv[4];
#pragma unroll
  for (int s2 = 0; s2 < 4; ++s2)
    rk[s2] = *(const u32x4*)(Kh + (size_t)(srow + s2 * 32) * 64 + schk * 8);
#pragma unroll
  for (int s2 = 0; s2 < 4; ++s2)
    rv[s2] = *(const u32x4*)(Vh + (size_t)(vrow + s2 * 16) * 2048 + vchk * 8);

  for (int kt = 0; kt <= qt; ++kt) {
    __syncthreads();   // prior-iter LDS reads (and iter0 qF reads) complete
#pragma unroll
    for (int s2 = 0; s2 < 4; ++s2)
      *(u32x4*)&Ks[(srow + s2 * 32) * LDK + schk * 8] = rk[s2];
#pragma unroll
    for (int s2 = 0; s2 < 4; ++s2)
      *(u32x4*)&Vts[(vrow + s2 * 16) * LDV + vchk * 8] = rv[s2];
    __syncthreads();

    // --- prefetch next K/V tile (overlaps all compute below) ---
    if (kt < qt) {
      const int kn = kt + 1;
#pragma unroll
      for (int s2 = 0; s2 < 4; ++s2)
        rk[s2] = *(const u32x4*)(Kh + (size_t)(kn * 128 + srow + s2 * 32) * 64 + schk * 8);
#pragma unroll
      for (int s2 = 0; s2 < 4; ++s2)
        rv[s2] = *(const u32x4*)(Vh + (size_t)(vrow + s2 * 16) * 2048 + kn * 128 + vchk * 8);
    }

    // --- S = Q K^T ---
    f32x4 S[2][8] = {};
#pragma unroll
    for (int nt = 0; nt < 8; ++nt) {
      const int kr = nt * 16 + l15;
#pragma unroll
      for (int k2 = 0; k2 < 2; ++k2) {
        const bf16x8 kF = *(const bf16x8*)&Ks[kr * LDK + k2 * 32 + quad * 8];
#pragma unroll
        for (int mt = 0; mt < 2; ++mt)
          S[mt][nt] = MFMA16(qF[mt][k2], kF, S[mt][nt]);
      }
    }

    // --- causal mask + online softmax; P (bf16) to wave-private LDS rows ---
    const bool diag = (kt == qt);
#pragma unroll
    for (int mt = 0; mt < 2; ++mt) {
#pragma unroll
      for (int r = 0; r < 4; ++r) {
        const int q = w * 32 + mt * 16 + quad * 4 + r;
        float sv[8], mx = -1e30f;
#pragma unroll
        for (int nt = 0; nt < 8; ++nt) {
          float s = S[mt][nt][r];
          if (diag && (nt * 16 + l15 > q)) s = -1e30f;
          sv[nt] = s;
          mx = fmaxf(mx, s);
        }
#pragma unroll
        for (int d = 1; d < 16; d <<= 1) mx = fmaxf(mx, __shfl_xor(mx, d));
        const float mnew  = fmaxf(mrow[mt][r], mx);
        const float alpha = exp2f((mrow[mt][r] - mnew) * sc_log2);
        mrow[mt][r] = mnew;
        float rs = 0.f;
#pragma unroll
        for (int nt = 0; nt < 8; ++nt) {
          const float p = exp2f((sv[nt] - mnew) * sc_log2);
          rs += p;
          Ps[q * LDP + nt * 16 + l15] = (bf16_t)p;
        }
#pragma unroll
        for (int d = 1; d < 16; d <<= 1) rs += __shfl_xor(rs, d);
        lrow[mt][r] = lrow[mt][r] * alpha + rs;
#pragma unroll
        for (int nt = 0; nt < 4; ++nt) O[mt][nt][r] *= alpha;
      }
    }

    // --- O += P V  (wave-private Ps rows; same-wave RAW, no barrier) ---
#pragma unroll
    for (int kk = 0; kk < 128; kk += 32) {
      const int co = kk + quad * 8;
      bf16x8 pF[2], vF[4];
#pragma unroll
      for (int mt = 0; mt < 2; ++mt)
        pF[mt] = *(const bf16x8*)&Ps[(w * 32 + mt * 16 + l15) * LDP + co];
#pragma unroll
      for (int nt = 0; nt < 4; ++nt)
        vF[nt] = *(const bf16x8*)&Vts[(nt * 16 + l15) * LDV + co];
#pragma unroll
      for (int mt = 0; mt < 2; ++mt)
#pragma unroll
        for (int nt = 0; nt < 4; ++nt)
          O[mt][nt] = MFMA16(pF[mt], vF[nt], O[mt][nt]);
    }
  }

  // --- epilogue: normalize, store ctx [B,S,1024] bf16 ---
#pragma unroll
  for (int mt = 0; mt < 2; ++mt) {
#pragma unroll
    for (int r = 0; r < 4; ++r) {
      const int s    = qt * 128 + w * 32 + mt * 16 + quad * 4 + r;
      const float iv = 1.f / lrow[mt][r];
#pragma unroll
      for (int nt = 0; nt < 4; ++nt) {
        const int hd = nt * 16 + l15;
        ctx[(size_t)(b * 2048 + s) * 1024 + h * 64 + hd] =
            (bf16_t)(O[mt][nt][r] * iv);
      }
    }
  }
}

// ---------------------------------------------------------------------------
extern "C" void kernel_launch(void* const* d_in, const int* in_sizes, int n_in,
                              void* d_out, int out_size, void* d_ws, size_t ws_size,
                              hipStream_t stream) {
  const float* x  = (const float*)d_in[0];
  const float* Wq = (const float*)d_in[1];
  const float* Wk = (const float*)d_in[2];
  const float* Wv = (const float*)d_in[3];
  const float* Wo = (const float*)d_in[4];
  const float* bo = (const float*)d_in[5];
  bf16_t* ws   = (bf16_t*)d_ws;
  bf16_t* Qw   = ws;                  // 4M bf16 elems each
  bf16_t* Kw   = ws + 4194304;
  bf16_t* Vw   = ws + 8388608;        // [B,H,64,S]
  bf16_t* ctxw = ws + 12582912;       // base pipeline: 32 MB
  float*  out  = (float*)d_out;       // fp32 per reference output dtype

  dim3 blk(256);
  const bool cvt = ws_size >= ((size_t)48 << 20);   // need 16 MB extra
  if (cvt) {
    bf16_t* xb  = ws + 16777216;      // 8 MB
    bf16_t* Wqb = ws + 20971520;      // 2 MB each
    bf16_t* Wkb = ws + 22020096;
    bf16_t* Wvb = ws + 23068672;
    bf16_t* Wob = ws + 24117248;      // ends at 48 MB exactly
    cvt_bf16<<<dim3(4096), blk, 0, stream>>>(x,  xb,  4194304);
    cvt_bf16<<<dim3(1024), blk, 0, stream>>>(Wq, Wqb, 1048576);
    cvt_bf16<<<dim3(1024), blk, 0, stream>>>(Wk, Wkb, 1048576);
    cvt_bf16<<<dim3(1024), blk, 0, stream>>>(Wv, Wvb, 1048576);
    cvt_bf16<<<dim3(1024), blk, 0, stream>>>(Wo, Wob, 1048576);
    gemm_qkv<bf16_t, bf16_t><<<dim3(8, 32, 3), blk, 0, stream>>>(
        xb, Wqb, Wkb, Wvb, Qw, Kw, Vw);
    attn<<<dim3(16, 16, 2), blk, 0, stream>>>(Qw, Kw, Vw, ctxw);
    gemm_out<bf16_t><<<dim3(8, 32, 1), blk, 0, stream>>>(ctxw, Wob, out, bo);
  } else {
    gemm_qkv<float, float><<<dim3(8, 32, 3), blk, 0, stream>>>(
        x, Wq, Wk, Wv, Qw, Kw, Vw);
    attn<<<dim3(16, 16, 2), blk, 0, stream>>>(Qw, Kw, Vw, ctxw);
    gemm_out<float><<<dim3(8, 32, 1), blk, 0, stream>>>(ctxw, Wo, out, bo);
  }
}

// Round 6
// 199.632 us; speedup vs baseline: 1.3765x; 1.1913x over previous
//
#include <hip/hip_runtime.h>
#include <stdint.h>

// ---------------------------------------------------------------------------
// MultiHeadAttention forward, MI355X/gfx950.  Round 6.
// fp32 I/O, bf16 MFMA compute. B=2 S=2048 D=1024 H=16 HD=64. M=4096.
// R6 changes vs R5 (passed, 237.8 us; attn 95 us, gemms ~133 us):
//  1) attn: transposed-S softmax. S^T = K*Q^T (swap MFMA operands) puts each
//     q-column in one lane (C/D col=l15=q, row=quad*4+r=key): row-softmax is
//     register-local + 2 shuffles (xor 16/32) instead of 4-deep x16 chains;
//     P stored with packed ds_write_b64 (4 contiguous keys) instead of 64
//     scalar conflicted b16 writes. alpha/lrow broadcast back to O-layout
//     via __shfl(v, quad*4+r).
//  2) GEMMs (bf16 path): global_load_lds width=16 staging with XOR swizzle
//     (phys_chunk = logical ^ (row&7)) applied on the GLOBAL source index;
//     LDS unpadded (async dest is wave-uniform-base + lane*16). m93->m97 was
//     1.69x on this exact step. fp32 fallback keeps register staging.
// MFMA mfma_f32_16x16x32_bf16 layouts [m89-verified]:
//   A-frag: lane(quad,l15) holds A[m=l15][k=quad*8+j]  (contig bf16x8)
//   B-frag: B[n=l15][k=quad*8+j];  C/D: col=l15, row=quad*4+reg
// ---------------------------------------------------------------------------

typedef __bf16 bf16_t;
typedef __bf16 bf16x8 __attribute__((ext_vector_type(8)));
typedef float  f32x4  __attribute__((ext_vector_type(4)));
typedef uint32_t u32x4 __attribute__((ext_vector_type(4)));

#define MFMA16(A, B, C) __builtin_amdgcn_mfma_f32_16x16x32_bf16(A, B, C, 0, 0, 0)

__device__ __forceinline__ void async_ld16(const bf16_t* g, bf16_t* l) {
  __builtin_amdgcn_global_load_lds(
      (const __attribute__((address_space(1))) void*)g,
      (__attribute__((address_space(3))) void*)l, 16, 0, 0);
}

__device__ __forceinline__ u32x4 ld8(const bf16_t* p) { return *(const u32x4*)p; }
__device__ __forceinline__ u32x4 ld8(const float* p) {
  const float4 a = *(const float4*)p;
  const float4 b = *(const float4*)(p + 4);
  union { u32x4 v; bf16_t h[8]; } r;
  r.h[0] = (bf16_t)a.x; r.h[1] = (bf16_t)a.y;
  r.h[2] = (bf16_t)a.z; r.h[3] = (bf16_t)a.w;
  r.h[4] = (bf16_t)b.x; r.h[5] = (bf16_t)b.y;
  r.h[6] = (bf16_t)b.z; r.h[7] = (bf16_t)b.w;
  return r.v;
}

// --- fp32 -> bf16 bulk converter -------------------------------------------
__global__ __launch_bounds__(256) void cvt_bf16(const float* __restrict__ s,
                                                bf16_t* __restrict__ d, int n) {
  const int i4 = (blockIdx.x * 256 + threadIdx.x) * 4;
  if (i4 >= n) return;
  const float4 v = *(const float4*)(s + i4);
  union { uint64_t u; bf16_t h[4]; } pk;
  pk.h[0] = (bf16_t)v.x; pk.h[1] = (bf16_t)v.y;
  pk.h[2] = (bf16_t)v.z; pk.h[3] = (bf16_t)v.w;
  *(uint64_t*)(d + i4) = pk.u;
}

// ---------------------------------------------------------------------------
// Shared GEMM epilogue. C/D: col = l15, row = quad*4 + reg.
// mode 0: Q/K [B,H,S,64] bf16; mode 1: V^T [B,H,64,S] bf16;
// mode 2: row-major FP32 + fp32 bias.
// ---------------------------------------------------------------------------
__device__ __forceinline__ void gemm_epilogue(
    f32x4 (&acc)[4][4], int bm, int bn, int wm, int wn, int quad, int l15,
    bf16_t* __restrict__ D, float* __restrict__ Dout,
    const float* __restrict__ bias, int mode) {
#pragma unroll
  for (int mt = 0; mt < 4; ++mt) {
#pragma unroll
    for (int nt = 0; nt < 4; ++nt) {
      const int n  = bn + wn + nt * 16 + l15;
      const int mb = bm + wm + mt * 16 + quad * 4;
      if (mode == 0) {               // Q/K: [B,H,S,64]
        const int h = n >> 6, hd = n & 63;
#pragma unroll
        for (int r = 0; r < 4; ++r) {
          const int m = mb + r;
          const int b = m >> 11, s = m & 2047;
          D[(size_t)b * 2097152 + (size_t)h * 131072 + (size_t)s * 64 + hd] =
              (bf16_t)acc[mt][nt][r];
        }
      } else if (mode == 1) {        // V^T: [B,H,64,S]; 4 consecutive tokens
        const int h = n >> 6, hd = n & 63;
        const int b = mb >> 11, s0 = mb & 2047;
        union { uint64_t u; bf16_t h4[4]; } pk;
#pragma unroll
        for (int r = 0; r < 4; ++r) pk.h4[r] = (bf16_t)acc[mt][nt][r];
        *(uint64_t*)(D + (size_t)b * 2097152 + (size_t)h * 131072 +
                     (size_t)hd * 2048 + s0) = pk.u;
      } else {                       // out: row-major FP32 + fp32 bias
        const float bv = bias[n];
#pragma unroll
        for (int r = 0; r < 4; ++r) {
          const int m = mb + r;
          Dout[(size_t)m * 1024 + n] = acc[mt][nt][r] + bv;
        }
      }
    }
  }
}

// ---------------------------------------------------------------------------
// Async-staged bf16 GEMM core (m97 structure): global_load_lds width=16,
// XOR swizzle on the global source chunk, unpadded LDS (128x64).
// D[m,n] = sum_k A[m,k]*W[n,k];  A: 4096x1024, W: 1024x1024, both bf16.
// ---------------------------------------------------------------------------
__device__ __forceinline__ void gemm_core_async(const bf16_t* __restrict__ A,
                                                const bf16_t* __restrict__ W,
                                                bf16_t* __restrict__ D,
                                                float* __restrict__ Dout,
                                                const float* __restrict__ bias,
                                                int mode) {
  __shared__ __align__(16) bf16_t As[128 * 64];
  __shared__ __align__(16) bf16_t Bs[128 * 64];

  const int tid  = threadIdx.x;
  const int lane = tid & 63;
  const int w    = tid >> 6;
  const int quad = lane >> 4;
  const int l15  = lane & 15;
  const int bm   = blockIdx.y * 128;
  const int bn   = blockIdx.x * 128;
  const int wm   = (w >> 1) * 64;
  const int wn   = (w & 1) * 64;
  const int sr   = lane >> 3;       // row within 8-row group
  const int sc   = lane & 7;        // physical 16B chunk

  f32x4 acc[4][4] = {};

  for (int k0 = 0; k0 < 1024; k0 += 64) {
#pragma unroll
    for (int j = 0; j < 4; ++j) {
      const int r0 = w * 32 + j * 8;               // wave-uniform LDS base row
      const int r  = r0 + sr;
      const int c  = sc ^ (r & 7);                 // swizzled global chunk
      async_ld16(A + (size_t)(bm + r) * 1024 + k0 + c * 8, &As[r0 * 64]);
      async_ld16(W + (size_t)(bn + r) * 1024 + k0 + c * 8, &Bs[r0 * 64]);
    }
    __syncthreads();    // drains vmcnt -> staged data visible
#pragma unroll
    for (int kk = 0; kk < 64; kk += 32) {
      const int ck = (kk >> 3) + quad;             // logical chunk
      bf16x8 aF[4], bF[4];
#pragma unroll
      for (int mt = 0; mt < 4; ++mt) {
        const int r = wm + mt * 16 + l15;
        aF[mt] = *(const bf16x8*)&As[r * 64 + (ck ^ (r & 7)) * 8];
      }
#pragma unroll
      for (int nt = 0; nt < 4; ++nt) {
        const int r = wn + nt * 16 + l15;
        bF[nt] = *(const bf16x8*)&Bs[r * 64 + (ck ^ (r & 7)) * 8];
      }
#pragma unroll
      for (int mt = 0; mt < 4; ++mt)
#pragma unroll
        for (int nt = 0; nt < 4; ++nt)
          acc[mt][nt] = MFMA16(aF[mt], bF[nt], acc[mt][nt]);
    }
    __syncthreads();    // all reads done before next staging overwrites
  }
  gemm_epilogue(acc, bm, bn, wm, wn, quad, l15, D, Dout, bias, mode);
}

// --- fp32-input fallback GEMM (register staging, padded LDS; R4-proven) ----
template <typename TA, typename TW>
__device__ __forceinline__ void gemm_core_reg(const TA* __restrict__ A,
                                              const TW* __restrict__ W,
                                              bf16_t* __restrict__ D,
                                              float* __restrict__ Dout,
                                              const float* __restrict__ bias,
                                              int mode) {
  constexpr int LDT = 72;
  __shared__ __align__(16) bf16_t As[128 * LDT];
  __shared__ __align__(16) bf16_t Bs[128 * LDT];

  const int tid  = threadIdx.x;
  const int lane = tid & 63;
  const int w    = tid >> 6;
  const int quad = lane >> 4;
  const int l15  = lane & 15;
  const int bm   = blockIdx.y * 128;
  const int bn   = blockIdx.x * 128;
  const int wm   = (w >> 1) * 64;
  const int wn   = (w & 1) * 64;
  const int srow = tid >> 3;
  const int schk = tid & 7;

  f32x4 acc[4][4] = {};

  for (int k0 = 0; k0 < 1024; k0 += 64) {
    u32x4 ra[4], rb[4];
#pragma unroll
    for (int s2 = 0; s2 < 4; ++s2) {
      const int r = srow + s2 * 32;
      ra[s2] = ld8(A + (size_t)(bm + r) * 1024 + k0 + schk * 8);
      rb[s2] = ld8(W + (size_t)(bn + r) * 1024 + k0 + schk * 8);
    }
    __syncthreads();
#pragma unroll
    for (int s2 = 0; s2 < 4; ++s2) {
      const int r = srow + s2 * 32;
      *(u32x4*)&As[r * LDT + schk * 8] = ra[s2];
      *(u32x4*)&Bs[r * LDT + schk * 8] = rb[s2];
    }
    __syncthreads();
#pragma unroll
    for (int kk = 0; kk < 64; kk += 32) {
      const int co = kk + quad * 8;
      bf16x8 aF[4], bF[4];
#pragma unroll
      for (int mt = 0; mt < 4; ++mt)
        aF[mt] = *(const bf16x8*)&As[(wm + mt * 16 + l15) * LDT + co];
#pragma unroll
      for (int nt = 0; nt < 4; ++nt)
        bF[nt] = *(const bf16x8*)&Bs[(wn + nt * 16 + l15) * LDT + co];
#pragma unroll
      for (int mt = 0; mt < 4; ++mt)
#pragma unroll
        for (int nt = 0; nt < 4; ++nt)
          acc[mt][nt] = MFMA16(aF[mt], bF[nt], acc[mt][nt]);
    }
  }
  gemm_epilogue(acc, bm, bn, wm, wn, quad, l15, D, Dout, bias, mode);
}

__global__ __launch_bounds__(256, 2) void gemm_qkv_a(
    const bf16_t* __restrict__ X,  const bf16_t* __restrict__ Wq,
    const bf16_t* __restrict__ Wk, const bf16_t* __restrict__ Wv,
    bf16_t* __restrict__ Q, bf16_t* __restrict__ K, bf16_t* __restrict__ V) {
  const int z = blockIdx.z;
  const bf16_t* W = (z == 0) ? Wq : (z == 1) ? Wk : Wv;
  bf16_t*       D = (z == 0) ? Q  : (z == 1) ? K  : V;
  gemm_core_async(X, W, D, nullptr, nullptr, (z == 2) ? 1 : 0);
}

__global__ __launch_bounds__(256, 2) void gemm_out_a(
    const bf16_t* __restrict__ ctx, const bf16_t* __restrict__ Wo,
    float* __restrict__ out, const float* __restrict__ bo) {
  gemm_core_async(ctx, Wo, nullptr, out, bo, 2);
}

__global__ __launch_bounds__(256, 2) void gemm_qkv_f(
    const float* __restrict__ X,  const float* __restrict__ Wq,
    const float* __restrict__ Wk, const float* __restrict__ Wv,
    bf16_t* __restrict__ Q, bf16_t* __restrict__ K, bf16_t* __restrict__ V) {
  const int z = blockIdx.z;
  const float* W = (z == 0) ? Wq : (z == 1) ? Wk : Wv;
  bf16_t*      D = (z == 0) ? Q  : (z == 1) ? K  : V;
  gemm_core_reg<float, float>(X, W, D, nullptr, nullptr, (z == 2) ? 1 : 0);
}

__global__ __launch_bounds__(256, 2) void gemm_out_f(
    const bf16_t* __restrict__ ctx, const float* __restrict__ Wo,
    float* __restrict__ out, const float* __restrict__ bo) {
  gemm_core_reg<bf16_t, float>(ctx, Wo, nullptr, out, bo, 2);
}

// ---------------------------------------------------------------------------
// Flash-style causal attention, transposed-S softmax. Grid (16,16,2), 256 thr.
// qt remap: z==0 -> x, z==1 -> 15-x (CU block-pairs sum to 17 K-tiles).
// Q,K: [B,H,S,64] bf16; V^T: [B,H,64,S] bf16; ctx: [B,S,1024] bf16.
// Wave w owns q-rows [w*32, w*32+32). LDS 69 KB -> 2 blocks/CU.
// S^T = MFMA(A=K, B=Q): lane(quad,l15) holds q=l15 (col), keys quad*4+r+16ntk.
// Softmax per q is register-local + shfl_xor(16,32); alpha/lrow broadcast to
// O-layout (q=quad*4+r) via __shfl(v, quad*4+r).
// ---------------------------------------------------------------------------
__global__ __launch_bounds__(256, 2) void attn(
    const bf16_t* __restrict__ Qw, const bf16_t* __restrict__ Kw,
    const bf16_t* __restrict__ Vw, bf16_t* __restrict__ ctx) {
  constexpr int LDK = 72, LDV = 136, LDP = 136;
  __shared__ __align__(16) bf16_t Ks[128 * LDK];
  __shared__ __align__(16) bf16_t Vts[64 * LDV];
  __shared__ __align__(16) bf16_t Ps[128 * LDP];

  const int tid  = threadIdx.x;
  const int lane = tid & 63;
  const int w    = tid >> 6;
  const int quad = lane >> 4;
  const int l15  = lane & 15;
  const int b    = blockIdx.z;
  const int qt   = (b == 0) ? blockIdx.x : 15 - blockIdx.x;
  const int h    = blockIdx.y;
  const size_t bh = (size_t)(b * 16 + h) * (size_t)(2048 * 64);
  const bf16_t* Qh = Qw + bh;
  const bf16_t* Kh = Kw + bh;
  const bf16_t* Vh = Vw + bh;       // [64][2048]

  const int srow = tid >> 3, schk = tid & 7;
  const int vrow = tid >> 4, vchk = tid & 15;

  bf16_t* Qs = Ps;                   // stage Q through Ps region (stride LDK)
  {
    u32x4 rq[4];
#pragma unroll
    for (int s2 = 0; s2 < 4; ++s2)
      rq[s2] = *(const u32x4*)(Qh + (size_t)(qt * 128 + srow + s2 * 32) * 64 + schk * 8);
#pragma unroll
    for (int s2 = 0; s2 < 4; ++s2)
      *(u32x4*)&Qs[(srow + s2 * 32) * LDK + schk * 8] = rq[s2];
  }
  __syncthreads();
  bf16x8 qF[2][2];
#pragma unroll
  for (int kq = 0; kq < 2; ++kq)
#pragma unroll
    for (int k2 = 0; k2 < 2; ++k2)
      qF[kq][k2] = *(const bf16x8*)
          &Qs[(w * 32 + kq * 16 + l15) * LDK + k2 * 32 + quad * 8];

  f32x4 O[2][4] = {};
  float mrow[2] = {-1e30f, -1e30f};
  float lrow[2] = {0.f, 0.f};

  const float sc_log2 = 0.125f * 1.44269504088896340736f;  // 1/sqrt(64)*log2e

  // --- preload kt=0 K/V tiles into registers ---
  u32x4 rk[4], rv[4];
#pragma unroll
  for (int s2 = 0; s2 < 4; ++s2)
    rk[s2] = *(const u32x4*)(Kh + (size_t)(srow + s2 * 32) * 64 + schk * 8);
#pragma unroll
  for (int s2 = 0; s2 < 4; ++s2)
    rv[s2] = *(const u32x4*)(Vh + (size_t)(vrow + s2 * 16) * 2048 + vchk * 8);

  for (int kt = 0; kt <= qt; ++kt) {
    __syncthreads();   // prior-iter LDS reads (and iter0 qF reads) complete
#pragma unroll
    for (int s2 = 0; s2 < 4; ++s2)
      *(u32x4*)&Ks[(srow + s2 * 32) * LDK + schk * 8] = rk[s2];
#pragma unroll
    for (int s2 = 0; s2 < 4; ++s2)
      *(u32x4*)&Vts[(vrow + s2 * 16) * LDV + vchk * 8] = rv[s2];
    __syncthreads();

    // --- prefetch next K/V tile (overlaps all compute below) ---
    if (kt < qt) {
      const int kn = kt + 1;
#pragma unroll
      for (int s2 = 0; s2 < 4; ++s2)
        rk[s2] = *(const u32x4*)(Kh + (size_t)(kn * 128 + srow + s2 * 32) * 64 + schk * 8);
#pragma unroll
      for (int s2 = 0; s2 < 4; ++s2)
        rv[s2] = *(const u32x4*)(Vh + (size_t)(vrow + s2 * 16) * 2048 + kn * 128 + vchk * 8);
    }

    // --- S^T = K Q^T : St[kq][ntk], q=l15 (col), key=ntk*16+quad*4+r ---
    f32x4 St[2][8] = {};
#pragma unroll
    for (int ntk = 0; ntk < 8; ++ntk) {
      const int kr = ntk * 16 + l15;           // key row for A-frag
#pragma unroll
      for (int k2 = 0; k2 < 2; ++k2) {
        const bf16x8 kF = *(const bf16x8*)&Ks[kr * LDK + k2 * 32 + quad * 8];
#pragma unroll
        for (int kq = 0; kq < 2; ++kq)
          St[kq][ntk] = MFMA16(kF, qF[kq][k2], St[kq][ntk]);
      }
    }

    // --- mask + online softmax (register-local per q-column) ---
    const bool diag = (kt == qt);
    float aq[2];
#pragma unroll
    for (int kq = 0; kq < 2; ++kq) {
      const int ql = w * 32 + kq * 16 + l15;   // block-local q row
      float mx = -1e30f;
#pragma unroll
      for (int ntk = 0; ntk < 8; ++ntk) {
#pragma unroll
        for (int r = 0; r < 4; ++r) {
          float s = St[kq][ntk][r];
          if (diag && (ntk * 16 + quad * 4 + r > ql)) s = -1e30f;
          St[kq][ntk][r] = s;
          mx = fmaxf(mx, s);
        }
      }
      mx = fmaxf(mx, __shfl_xor(mx, 16));
      mx = fmaxf(mx, __shfl_xor(mx, 32));
      const float mnew  = fmaxf(mrow[kq], mx);
      const float alpha = exp2f((mrow[kq] - mnew) * sc_log2);
      mrow[kq] = mnew;
      float rs = 0.f;
#pragma unroll
      for (int ntk = 0; ntk < 8; ++ntk) {
        union { uint64_t u; bf16_t h4[4]; } pk;
#pragma unroll
        for (int r = 0; r < 4; ++r) {
          const float p = exp2f((St[kq][ntk][r] - mnew) * sc_log2);
          rs += p;
          pk.h4[r] = (bf16_t)p;
        }
        *(uint64_t*)&Ps[(w * 32 + kq * 16 + l15) * LDP + ntk * 16 + quad * 4] = pk.u;
      }
      rs += __shfl_xor(rs, 16);
      rs += __shfl_xor(rs, 32);
      lrow[kq] = lrow[kq] * alpha + rs;
      aq[kq] = alpha;
    }

    // --- rescale O by alpha (broadcast to O layout q=quad*4+r) ---
#pragma unroll
    for (int mt = 0; mt < 2; ++mt) {
#pragma unroll
      for (int r = 0; r < 4; ++r) {
        const float a = __shfl(aq[mt], quad * 4 + r);
#pragma unroll
        for (int nt = 0; nt < 4; ++nt) O[mt][nt][r] *= a;
      }
    }

    // --- O += P V  (wave-private Ps rows; same-wave RAW, no barrier) ---
#pragma unroll
    for (int kk = 0; kk < 128; kk += 32) {
      const int co = kk + quad * 8;
      bf16x8 pF[2], vF[4];
#pragma unroll
      for (int mt = 0; mt < 2; ++mt)
        pF[mt] = *(const bf16x8*)&Ps[(w * 32 + mt * 16 + l15) * LDP + co];
#pragma unroll
      for (int nt = 0; nt < 4; ++nt)
        vF[nt] = *(const bf16x8*)&Vts[(nt * 16 + l15) * LDV + co];
#pragma unroll
      for (int mt = 0; mt < 2; ++mt)
#pragma unroll
        for (int nt = 0; nt < 4; ++nt)
          O[mt][nt] = MFMA16(pF[mt], vF[nt], O[mt][nt]);
    }
  }

  // --- epilogue: normalize (lrow broadcast from q-column lanes), store ---
#pragma unroll
  for (int mt = 0; mt < 2; ++mt) {
#pragma unroll
    for (int r = 0; r < 4; ++r) {
      const float lr = __shfl(lrow[mt], quad * 4 + r);
      const float iv = 1.f / lr;
      const int s = qt * 128 + w * 32 + mt * 16 + quad * 4 + r;
#pragma unroll
      for (int nt = 0; nt < 4; ++nt) {
        const int hd = nt * 16 + l15;
        ctx[(size_t)(b * 2048 + s) * 1024 + h * 64 + hd] =
            (bf16_t)(O[mt][nt][r] * iv);
      }
    }
  }
}

// ---------------------------------------------------------------------------
extern "C" void kernel_launch(void* const* d_in, const int* in_sizes, int n_in,
                              void* d_out, int out_size, void* d_ws, size_t ws_size,
                              hipStream_t stream) {
  const float* x  = (const float*)d_in[0];
  const float* Wq = (const float*)d_in[1];
  const float* Wk = (const float*)d_in[2];
  const float* Wv = (const float*)d_in[3];
  const float* Wo = (const float*)d_in[4];
  const float* bo = (const float*)d_in[5];
  bf16_t* ws   = (bf16_t*)d_ws;
  bf16_t* Qw   = ws;                  // 4M bf16 elems each
  bf16_t* Kw   = ws + 4194304;
  bf16_t* Vw   = ws + 8388608;        // [B,H,64,S]
  bf16_t* ctxw = ws + 12582912;       // base pipeline: 32 MB
  float*  out  = (float*)d_out;       // fp32 per reference output dtype

  dim3 blk(256);
  const bool cvt = ws_size >= ((size_t)48 << 20);   // need 16 MB extra
  if (cvt) {
    bf16_t* xb  = ws + 16777216;      // 8 MB
    bf16_t* Wqb = ws + 20971520;      // 2 MB each
    bf16_t* Wkb = ws + 22020096;
    bf16_t* Wvb = ws + 23068672;
    bf16_t* Wob = ws + 24117248;      // ends at 48 MB exactly
    cvt_bf16<<<dim3(4096), blk, 0, stream>>>(x,  xb,  4194304);
    cvt_bf16<<<dim3(1024), blk, 0, stream>>>(Wq, Wqb, 1048576);
    cvt_bf16<<<dim3(1024), blk, 0, stream>>>(Wk, Wkb, 1048576);
    cvt_bf16<<<dim3(1024), blk, 0, stream>>>(Wv, Wvb, 1048576);
    cvt_bf16<<<dim3(1024), blk, 0, stream>>>(Wo, Wob, 1048576);
    gemm_qkv_a<<<dim3(8, 32, 3), blk, 0, stream>>>(xb, Wqb, Wkb, Wvb, Qw, Kw, Vw);
    attn<<<dim3(16, 16, 2), blk, 0, stream>>>(Qw, Kw, Vw, ctxw);
    gemm_out_a<<<dim3(8, 32, 1), blk, 0, stream>>>(ctxw, Wob, out, bo);
  } else {
    gemm_qkv_f<<<dim3(8, 32, 3), blk, 0, stream>>>(x, Wq, Wk, Wv, Qw, Kw, Vw);
    attn<<<dim3(16, 16, 2), blk, 0, stream>>>(Qw, Kw, Vw, ctxw);
    gemm_out_f<<<dim3(8, 32, 1), blk, 0, stream>>>(ctxw, Wo, out, bo);
  }
}

// Round 7
// 190.775 us; speedup vs baseline: 1.4405x; 1.0464x over previous
//
#include <hip/hip_runtime.h>
#include <stdint.h>

// ---------------------------------------------------------------------------
// MultiHeadAttention forward, MI355X/gfx950.  Round 7.
// fp32 I/O, bf16 MFMA compute. B=2 S=2048 D=1024 H=16 HD=64. M=4096.
// R7 vs R6 (passed, 199.6 us; attn 63, gemms+cvt ~137):
//  KEY FIX: R5/R6's bf16+global_load_lds GEMM path never ran (ws_size<48MB
//  guard failed -> fp32 register fallback). Now the cvt scratch lives in
//  d_out (16 MB, write-only until the final GEMM):
//    cvt x,Wq,Wk,Wv -> d_out (14 MB bf16)   [d_out not read until the end]
//    gemm_qkv_a (async staged) -> Q,K,V in ws
//    attn -> ctx in ws
//    cvt Wo -> ws@Qw (Q dead after attn)
//    gemm_out_a -> fp32 out over d_out (scratch dead by then; same stream)
//  ws use: exactly 32 MB (R4-proven safe). No fallback path.
//  attn: diag masking branched out of non-diagonal iterations.
// MFMA mfma_f32_16x16x32_bf16 layouts [m89-verified]:
//   A-frag: lane(quad,l15) holds A[m=l15][k=quad*8+j]  (contig bf16x8)
//   B-frag: B[n=l15][k=quad*8+j];  C/D: col=l15, row=quad*4+reg
// Async staging swizzle: LDS[r][pc] = G[r][pc^(r&7)]; frag reads ck^(r&7).
// ---------------------------------------------------------------------------

typedef __bf16 bf16_t;
typedef __bf16 bf16x8 __attribute__((ext_vector_type(8)));
typedef float  f32x4  __attribute__((ext_vector_type(4)));
typedef uint32_t u32x4 __attribute__((ext_vector_type(4)));

#define MFMA16(A, B, C) __builtin_amdgcn_mfma_f32_16x16x32_bf16(A, B, C, 0, 0, 0)

__device__ __forceinline__ void async_ld16(const bf16_t* g, bf16_t* l) {
  __builtin_amdgcn_global_load_lds(
      (const __attribute__((address_space(1))) void*)g,
      (__attribute__((address_space(3))) void*)l, 16, 0, 0);
}

// --- fp32 -> bf16 bulk converters ------------------------------------------
__global__ __launch_bounds__(256) void cvt_x(const float* __restrict__ s,
                                             bf16_t* __restrict__ d) {
  const int i4 = (blockIdx.x * 256 + threadIdx.x) * 4;   // grid covers exactly n
  const float4 v = *(const float4*)(s + i4);
  union { uint64_t u; bf16_t h[4]; } pk;
  pk.h[0] = (bf16_t)v.x; pk.h[1] = (bf16_t)v.y;
  pk.h[2] = (bf16_t)v.z; pk.h[3] = (bf16_t)v.w;
  *(uint64_t*)(d + i4) = pk.u;
}

__global__ __launch_bounds__(256) void cvt_w3(
    const float* __restrict__ s0, const float* __restrict__ s1,
    const float* __restrict__ s2, bf16_t* __restrict__ d0,
    bf16_t* __restrict__ d1, bf16_t* __restrict__ d2) {
  const int z = blockIdx.y;
  const float* s = (z == 0) ? s0 : (z == 1) ? s1 : s2;
  bf16_t*      d = (z == 0) ? d0 : (z == 1) ? d1 : d2;
  const int i4 = (blockIdx.x * 256 + threadIdx.x) * 4;
  const float4 v = *(const float4*)(s + i4);
  union { uint64_t u; bf16_t h[4]; } pk;
  pk.h[0] = (bf16_t)v.x; pk.h[1] = (bf16_t)v.y;
  pk.h[2] = (bf16_t)v.z; pk.h[3] = (bf16_t)v.w;
  *(uint64_t*)(d + i4) = pk.u;
}

// ---------------------------------------------------------------------------
// Async-staged bf16 GEMM core (m97 structure): global_load_lds width=16,
// XOR swizzle on the global source chunk, unpadded LDS (128x64).
// D[m,n] = sum_k A[m,k]*W[n,k];  A: 4096x1024, W: 1024x1024, both bf16.
// mode 0: Q/K [B,H,S,64]; mode 1: V^T [B,H,64,S]; mode 2: row-major FP32+bias.
// ---------------------------------------------------------------------------
__device__ __forceinline__ void gemm_core_async(const bf16_t* __restrict__ A,
                                                const bf16_t* __restrict__ W,
                                                bf16_t* __restrict__ D,
                                                float* __restrict__ Dout,
                                                const float* __restrict__ bias,
                                                int mode) {
  __shared__ __align__(16) bf16_t As[128 * 64];
  __shared__ __align__(16) bf16_t Bs[128 * 64];

  const int tid  = threadIdx.x;
  const int lane = tid & 63;
  const int w    = tid >> 6;
  const int quad = lane >> 4;
  const int l15  = lane & 15;
  const int bm   = blockIdx.y * 128;
  const int bn   = blockIdx.x * 128;
  const int wm   = (w >> 1) * 64;
  const int wn   = (w & 1) * 64;
  const int sr   = lane >> 3;       // row within 8-row group
  const int sc   = lane & 7;        // physical 16B chunk

  f32x4 acc[4][4] = {};

  for (int k0 = 0; k0 < 1024; k0 += 64) {
#pragma unroll
    for (int j = 0; j < 4; ++j) {
      const int r0 = w * 32 + j * 8;               // wave-uniform LDS base row
      const int r  = r0 + sr;
      const int c  = sc ^ (r & 7);                 // swizzled global chunk
      async_ld16(A + (size_t)(bm + r) * 1024 + k0 + c * 8, &As[r0 * 64]);
      async_ld16(W + (size_t)(bn + r) * 1024 + k0 + c * 8, &Bs[r0 * 64]);
    }
    __syncthreads();    // drains vmcnt -> staged data visible
#pragma unroll
    for (int kk = 0; kk < 64; kk += 32) {
      const int ck = (kk >> 3) + quad;             // logical chunk
      bf16x8 aF[4], bF[4];
#pragma unroll
      for (int mt = 0; mt < 4; ++mt) {
        const int r = wm + mt * 16 + l15;
        aF[mt] = *(const bf16x8*)&As[r * 64 + (ck ^ (r & 7)) * 8];
      }
#pragma unroll
      for (int nt = 0; nt < 4; ++nt) {
        const int r = wn + nt * 16 + l15;
        bF[nt] = *(const bf16x8*)&Bs[r * 64 + (ck ^ (r & 7)) * 8];
      }
#pragma unroll
      for (int mt = 0; mt < 4; ++mt)
#pragma unroll
        for (int nt = 0; nt < 4; ++nt)
          acc[mt][nt] = MFMA16(aF[mt], bF[nt], acc[mt][nt]);
    }
    __syncthreads();    // all reads done before next staging overwrites
  }

  // Epilogue. C/D: col = l15, row = quad*4 + reg.
#pragma unroll
  for (int mt = 0; mt < 4; ++mt) {
#pragma unroll
    for (int nt = 0; nt < 4; ++nt) {
      const int n  = bn + wn + nt * 16 + l15;
      const int mb = bm + wm + mt * 16 + quad * 4;
      if (mode == 0) {               // Q/K: [B,H,S,64]
        const int h = n >> 6, hd = n & 63;
#pragma unroll
        for (int r = 0; r < 4; ++r) {
          const int m = mb + r;
          const int b = m >> 11, s = m & 2047;
          D[(size_t)b * 2097152 + (size_t)h * 131072 + (size_t)s * 64 + hd] =
              (bf16_t)acc[mt][nt][r];
        }
      } else if (mode == 1) {        // V^T: [B,H,64,S]; 4 consecutive tokens
        const int h = n >> 6, hd = n & 63;
        const int b = mb >> 11, s0 = mb & 2047;
        union { uint64_t u; bf16_t h4[4]; } pk;
#pragma unroll
        for (int r = 0; r < 4; ++r) pk.h4[r] = (bf16_t)acc[mt][nt][r];
        *(uint64_t*)(D + (size_t)b * 2097152 + (size_t)h * 131072 +
                     (size_t)hd * 2048 + s0) = pk.u;
      } else {                       // out: row-major FP32 + fp32 bias
        const float bv = bias[n];
#pragma unroll
        for (int r = 0; r < 4; ++r) {
          const int m = mb + r;
          Dout[(size_t)m * 1024 + n] = acc[mt][nt][r] + bv;
        }
      }
    }
  }
}

__global__ __launch_bounds__(256, 2) void gemm_qkv_a(
    const bf16_t* __restrict__ X,  const bf16_t* __restrict__ Wq,
    const bf16_t* __restrict__ Wk, const bf16_t* __restrict__ Wv,
    bf16_t* __restrict__ Q, bf16_t* __restrict__ K, bf16_t* __restrict__ V) {
  const int z = blockIdx.z;
  const bf16_t* W = (z == 0) ? Wq : (z == 1) ? Wk : Wv;
  bf16_t*       D = (z == 0) ? Q  : (z == 1) ? K  : V;
  gemm_core_async(X, W, D, nullptr, nullptr, (z == 2) ? 1 : 0);
}

__global__ __launch_bounds__(256, 2) void gemm_out_a(
    const bf16_t* __restrict__ ctx, const bf16_t* __restrict__ Wo,
    float* __restrict__ out, const float* __restrict__ bo) {
  gemm_core_async(ctx, Wo, nullptr, out, bo, 2);
}

// ---------------------------------------------------------------------------
// Flash-style causal attention, transposed-S softmax. Grid (16,16,2), 256 thr.
// qt remap: z==0 -> x, z==1 -> 15-x (CU block-pairs sum to 17 K-tiles).
// Q,K: [B,H,S,64] bf16; V^T: [B,H,64,S] bf16; ctx: [B,S,1024] bf16.
// Wave w owns q-rows [w*32, w*32+32). LDS 69 KB -> 2 blocks/CU.
// S^T = MFMA(A=K, B=Q): q=l15 (col), key=ntk*16+quad*4+r.  Softmax is
// register-local + shfl_xor(16,32); alpha/lrow broadcast via __shfl.
// Diagonal masking branched out of non-diagonal iterations (wave-uniform).
// ---------------------------------------------------------------------------
__global__ __launch_bounds__(256, 2) void attn(
    const bf16_t* __restrict__ Qw, const bf16_t* __restrict__ Kw,
    const bf16_t* __restrict__ Vw, bf16_t* __restrict__ ctx) {
  constexpr int LDK = 72, LDV = 136, LDP = 136;
  __shared__ __align__(16) bf16_t Ks[128 * LDK];
  __shared__ __align__(16) bf16_t Vts[64 * LDV];
  __shared__ __align__(16) bf16_t Ps[128 * LDP];

  const int tid  = threadIdx.x;
  const int lane = tid & 63;
  const int w    = tid >> 6;
  const int quad = lane >> 4;
  const int l15  = lane & 15;
  const int b    = blockIdx.z;
  const int qt   = (b == 0) ? blockIdx.x : 15 - blockIdx.x;
  const int h    = blockIdx.y;
  const size_t bh = (size_t)(b * 16 + h) * (size_t)(2048 * 64);
  const bf16_t* Qh = Qw + bh;
  const bf16_t* Kh = Kw + bh;
  const bf16_t* Vh = Vw + bh;       // [64][2048]

  const int srow = tid >> 3, schk = tid & 7;
  const int vrow = tid >> 4, vchk = tid & 15;

  bf16_t* Qs = Ps;                   // stage Q through Ps region (stride LDK)
  {
    u32x4 rq[4];
#pragma unroll
    for (int s2 = 0; s2 < 4; ++s2)
      rq[s2] = *(const u32x4*)(Qh + (size_t)(qt * 128 + srow + s2 * 32) * 64 + schk * 8);
#pragma unroll
    for (int s2 = 0; s2 < 4; ++s2)
      *(u32x4*)&Qs[(srow + s2 * 32) * LDK + schk * 8] = rq[s2];
  }
  __syncthreads();
  bf16x8 qF[2][2];
#pragma unroll
  for (int kq = 0; kq < 2; ++kq)
#pragma unroll
    for (int k2 = 0; k2 < 2; ++k2)
      qF[kq][k2] = *(const bf16x8*)
          &Qs[(w * 32 + kq * 16 + l15) * LDK + k2 * 32 + quad * 8];

  f32x4 O[2][4] = {};
  float mrow[2] = {-1e30f, -1e30f};
  float lrow[2] = {0.f, 0.f};

  const float sc_log2 = 0.125f * 1.44269504088896340736f;  // 1/sqrt(64)*log2e

  // --- preload kt=0 K/V tiles into registers ---
  u32x4 rk[4], rv[4];
#pragma unroll
  for (int s2 = 0; s2 < 4; ++s2)
    rk[s2] = *(const u32x4*)(Kh + (size_t)(srow + s2 * 32) * 64 + schk * 8);
#pragma unroll
  for (int s2 = 0; s2 < 4; ++s2)
    rv[s2] = *(const u32x4*)(Vh + (size_t)(vrow + s2 * 16) * 2048 + vchk * 8);

  for (int kt = 0; kt <= qt; ++kt) {
    __syncthreads();   // prior-iter LDS reads (and iter0 qF reads) complete
#pragma unroll
    for (int s2 = 0; s2 < 4; ++s2)
      *(u32x4*)&Ks[(srow + s2 * 32) * LDK + schk * 8] = rk[s2];
#pragma unroll
    for (int s2 = 0; s2 < 4; ++s2)
      *(u32x4*)&Vts[(vrow + s2 * 16) * LDV + vchk * 8] = rv[s2];
    __syncthreads();

    // --- prefetch next K/V tile (overlaps all compute below) ---
    if (kt < qt) {
      const int kn = kt + 1;
#pragma unroll
      for (int s2 = 0; s2 < 4; ++s2)
        rk[s2] = *(const u32x4*)(Kh + (size_t)(kn * 128 + srow + s2 * 32) * 64 + schk * 8);
#pragma unroll
      for (int s2 = 0; s2 < 4; ++s2)
        rv[s2] = *(const u32x4*)(Vh + (size_t)(vrow + s2 * 16) * 2048 + kn * 128 + vchk * 8);
    }

    // --- S^T = K Q^T : St[kq][ntk], q=l15 (col), key=ntk*16+quad*4+r ---
    f32x4 St[2][8] = {};
#pragma unroll
    for (int ntk = 0; ntk < 8; ++ntk) {
      const int kr = ntk * 16 + l15;           // key row for A-frag
#pragma unroll
      for (int k2 = 0; k2 < 2; ++k2) {
        const bf16x8 kF = *(const bf16x8*)&Ks[kr * LDK + k2 * 32 + quad * 8];
#pragma unroll
        for (int kq = 0; kq < 2; ++kq)
          St[kq][ntk] = MFMA16(kF, qF[kq][k2], St[kq][ntk]);
      }
    }

    // --- diag mask only on the diagonal tile (wave-uniform branch) ---
    if (kt == qt) {
#pragma unroll
      for (int kq = 0; kq < 2; ++kq) {
        const int ql = w * 32 + kq * 16 + l15;
#pragma unroll
        for (int ntk = 0; ntk < 8; ++ntk)
#pragma unroll
          for (int r = 0; r < 4; ++r)
            if (ntk * 16 + quad * 4 + r > ql) St[kq][ntk][r] = -1e30f;
      }
    }

    // --- online softmax (register-local per q-column) ---
    float aq[2];
#pragma unroll
    for (int kq = 0; kq < 2; ++kq) {
      float mx = -1e30f;
#pragma unroll
      for (int ntk = 0; ntk < 8; ++ntk)
#pragma unroll
        for (int r = 0; r < 4; ++r) mx = fmaxf(mx, St[kq][ntk][r]);
      mx = fmaxf(mx, __shfl_xor(mx, 16));
      mx = fmaxf(mx, __shfl_xor(mx, 32));
      const float mnew  = fmaxf(mrow[kq], mx);
      const float alpha = exp2f((mrow[kq] - mnew) * sc_log2);
      mrow[kq] = mnew;
      float rs = 0.f;
#pragma unroll
      for (int ntk = 0; ntk < 8; ++ntk) {
        union { uint64_t u; bf16_t h4[4]; } pk;
#pragma unroll
        for (int r = 0; r < 4; ++r) {
          const float p = exp2f((St[kq][ntk][r] - mnew) * sc_log2);
          rs += p;
          pk.h4[r] = (bf16_t)p;
        }
        *(uint64_t*)&Ps[(w * 32 + kq * 16 + l15) * LDP + ntk * 16 + quad * 4] = pk.u;
      }
      rs += __shfl_xor(rs, 16);
      rs += __shfl_xor(rs, 32);
      lrow[kq] = lrow[kq] * alpha + rs;
      aq[kq] = alpha;
    }

    // --- rescale O by alpha (broadcast to O layout q=quad*4+r) ---
#pragma unroll
    for (int mt = 0; mt < 2; ++mt) {
#pragma unroll
      for (int r = 0; r < 4; ++r) {
        const float a = __shfl(aq[mt], quad * 4 + r);
#pragma unroll
        for (int nt = 0; nt < 4; ++nt) O[mt][nt][r] *= a;
      }
    }

    // --- O += P V  (wave-private Ps rows; same-wave RAW, no barrier) ---
#pragma unroll
    for (int kk = 0; kk < 128; kk += 32) {
      const int co = kk + quad * 8;
      bf16x8 pF[2], vF[4];
#pragma unroll
      for (int mt = 0; mt < 2; ++mt)
        pF[mt] = *(const bf16x8*)&Ps[(w * 32 + mt * 16 + l15) * LDP + co];
#pragma unroll
      for (int nt = 0; nt < 4; ++nt)
        vF[nt] = *(const bf16x8*)&Vts[(nt * 16 + l15) * LDV + co];
#pragma unroll
      for (int mt = 0; mt < 2; ++mt)
#pragma unroll
        for (int nt = 0; nt < 4; ++nt)
          O[mt][nt] = MFMA16(pF[mt], vF[nt], O[mt][nt]);
    }
  }

  // --- epilogue: normalize (lrow broadcast from q-column lanes), store ---
#pragma unroll
  for (int mt = 0; mt < 2; ++mt) {
#pragma unroll
    for (int r = 0; r < 4; ++r) {
      const float lr = __shfl(lrow[mt], quad * 4 + r);
      const float iv = 1.f / lr;
      const int s = qt * 128 + w * 32 + mt * 16 + quad * 4 + r;
#pragma unroll
      for (int nt = 0; nt < 4; ++nt) {
        const int hd = nt * 16 + l15;
        ctx[(size_t)(b * 2048 + s) * 1024 + h * 64 + hd] =
            (bf16_t)(O[mt][nt][r] * iv);
      }
    }
  }
}

// ---------------------------------------------------------------------------
extern "C" void kernel_launch(void* const* d_in, const int* in_sizes, int n_in,
                              void* d_out, int out_size, void* d_ws, size_t ws_size,
                              hipStream_t stream) {
  const float* x  = (const float*)d_in[0];
  const float* Wq = (const float*)d_in[1];
  const float* Wk = (const float*)d_in[2];
  const float* Wv = (const float*)d_in[3];
  const float* Wo = (const float*)d_in[4];
  const float* bo = (const float*)d_in[5];

  bf16_t* ws   = (bf16_t*)d_ws;       // ws: exactly 32 MB used
  bf16_t* Qw   = ws;                  // 4M bf16 elems each
  bf16_t* Kw   = ws + 4194304;
  bf16_t* Vw   = ws + 8388608;        // [B,H,64,S]
  bf16_t* ctxw = ws + 12582912;
  bf16_t* Wob  = Qw;                  // Q region reused after attn

  bf16_t* dscr = (bf16_t*)d_out;      // d_out as bf16 scratch (14 of 16 MB)
  bf16_t* xb   = dscr;                // 8 MB
  bf16_t* Wqb  = dscr + 4194304;      // 2 MB each
  bf16_t* Wkb  = dscr + 5242880;
  bf16_t* Wvb  = dscr + 6291456;      // ends at 14 MB
  float*  out  = (float*)d_out;       // final fp32 output overwrites scratch

  dim3 blk(256);
  cvt_x<<<dim3(4096), blk, 0, stream>>>(x, xb);
  cvt_w3<<<dim3(1024, 3), blk, 0, stream>>>(Wq, Wk, Wv, Wqb, Wkb, Wvb);
  gemm_qkv_a<<<dim3(8, 32, 3), blk, 0, stream>>>(xb, Wqb, Wkb, Wvb, Qw, Kw, Vw);
  attn<<<dim3(16, 16, 2), blk, 0, stream>>>(Qw, Kw, Vw, ctxw);
  cvt_x<<<dim3(1024), blk, 0, stream>>>(Wo, Wob);   // 1M elems: 1024 blocks
  gemm_out_a<<<dim3(8, 32, 1), blk, 0, stream>>>(ctxw, Wob, out, bo);
}